// Round 10
// baseline (546.223 us; speedup 1.0000x reference)
//
#include <hip/hip_runtime.h>
#include <math.h>

typedef _Float16 f16x8 __attribute__((ext_vector_type(8)));
typedef float f32x4 __attribute__((ext_vector_type(4)));

#define NB 16
#define CC 1024
#define HW 1024
#define CQK 128
#define EPS 1e-5f

// ---- ws byte offsets (~112 MiB) ----
#define OFF_A     0
#define OFF_STATS 65536
#define OFF_CM    66048
#define OFF_WH    131584                    /* W fp16 [1280][1024] = 2.5 MB */
#define OFF_QT    (OFF_WH + 2621440)        /* qT fp16 [16][1024][128] = 4 MB */
#define OFF_KT    (OFF_QT + 4194304)
#define OFF_V     (OFF_KT + 4194304)        /* v fp16 [16][1024][1024] = 32 MB */
#define OFF_XH    (OFF_V + 33554432)        /* xT fp16 [16][1024][1024] = 32 MB */
#define OFF_ATTN  OFF_XH                    /* attn fp32 64 MB overlays XH (dead after qkv) */
#define OFF_PMAX  (OFF_ATTN + 67108864)
#define OFF_YP    OFF_V                     /* conv partials, dead before qkv */

__device__ __forceinline__ ushort f16b(float f) {
    union { _Float16 h; ushort u; } v;
    v.h = (_Float16)f;
    return v.u;
}

// ============ cvtT_x + fused conv 9-tap partials ============
__global__ __launch_bounds__(256) void cvtT_x_conv(
        const float* __restrict__ x, const float* __restrict__ hwt,
        ushort* __restrict__ xh, float* __restrict__ yp) {
    int n = blockIdx.z, cb = blockIdx.y, hb = blockIdx.x;
    __shared__ float tile[32][33];
    int t = threadIdx.x;
    int r = t >> 3, c4 = (t & 7) << 2;
    const float* s = x + ((size_t)(n * CC + cb * 32 + r) << 10) + hb * 32 + c4;
    float4 v = *(const float4*)s;
    tile[r][c4] = v.x; tile[r][c4 + 1] = v.y; tile[r][c4 + 2] = v.z; tile[r][c4 + 3] = v.w;
    __syncthreads();
    int hw_l = t >> 3, cg = (t & 7) << 2;
    ushort4 h4;
    h4.x = f16b(tile[cg + 0][hw_l]); h4.y = f16b(tile[cg + 1][hw_l]);
    h4.z = f16b(tile[cg + 2][hw_l]); h4.w = f16b(tile[cg + 3][hw_l]);
    *(ushort4*)&xh[((size_t)(n * HW + hb * 32 + hw_l) << 10) + cb * 32 + cg] = h4;
    float pacc[9] = {};
    #pragma unroll
    for (int cc = 0; cc < 4; ++cc) {
        float xv = tile[cg + cc][hw_l];
        const float* w9 = hwt + (cb * 32 + cg + cc) * 9;
        #pragma unroll
        for (int tp = 0; tp < 9; ++tp) pacc[tp] += xv * w9[tp];
    }
    #pragma unroll
    for (int off = 1; off < 8; off <<= 1)
        #pragma unroll
        for (int tp = 0; tp < 9; ++tp) pacc[tp] += __shfl_xor(pacc[tp], off);
    if ((t & 7) == 0) {
        #pragma unroll
        for (int tp = 0; tp < 9; ++tp)
            yp[(((size_t)(n * 32 + cb) * 9 + tp) << 10) + hb * 32 + hw_l] = pacc[tp];
    }
}

__global__ __launch_bounds__(256) void conv_combine(
        const float* __restrict__ yp, float* __restrict__ a) {
    int idx = blockIdx.x * 256 + threadIdx.x;
    int n = idx >> 10, p = idx & 1023;
    int h = p >> 5, w = p & 31;
    float s = 0.f;
    #pragma unroll
    for (int tp = 0; tp < 9; ++tp) {
        int dy = tp / 3 - 1, dx = tp % 3 - 1;
        int hh = h + dy, ww = w + dx;
        if (hh < 0 || hh > 31 || ww < 0 || ww > 31) continue;
        int pp = (hh << 5) + ww;
        const float* b = yp + (((size_t)(n * 32) * 9) << 10) + ((size_t)tp << 10) + pp;
        #pragma unroll
        for (int cch = 0; cch < 32; ++cch) s += b[((size_t)cch * 9) << 10];
    }
    a[idx] = s;
}

// ============ small kernels ============
__global__ void bn_stats(const float* __restrict__ a, float* __restrict__ stats) {
    int t = threadIdx.x;
    float s = 0.f, ss = 0.f;
    for (int i = t; i < NB * HW; i += 256) { float v = a[i]; s += v; ss += v * v; }
    __shared__ float rs[256], rss[256];
    rs[t] = s; rss[t] = ss;
    __syncthreads();
    for (int off = 128; off > 0; off >>= 1) {
        if (t < off) { rs[t] += rs[t + off]; rss[t] += rss[t + off]; }
        __syncthreads();
    }
    if (t == 0) {
        float mu = rs[0] / (NB * HW);
        float var = rss[0] / (NB * HW) - mu * mu;
        stats[0] = mu;
        stats[1] = rsqrtf(var + EPS);
    }
}

__global__ void ccam_kernel(const float* __restrict__ a, const float* __restrict__ stats,
                            const float* __restrict__ bn_w, const float* __restrict__ bn_b,
                            float* __restrict__ cm, float* __restrict__ out_ccam) {
    int i = blockIdx.x * 256 + threadIdx.x;
    float z = (a[i] - stats[0]) * stats[1] * bn_w[0] + bn_b[0];
    float sg = 1.f / (1.f + expf(-z));
    cm[i] = sg;
    out_ccam[i] = sg;
}

__global__ void fgbg_kernel(const float* __restrict__ x, const float* __restrict__ cm,
                            float* __restrict__ out_fg, float* __restrict__ out_bg) {
    int gid = blockIdx.x * blockDim.x + threadIdx.x;
    int wid = gid >> 6;
    int lane = threadIdx.x & 63;
    int n = wid >> 10, c = wid & 1023;
    const float4* xp = (const float4*)(x + ((size_t)(n * CC + c) << 10));
    const float4* cp = (const float4*)(cm + (n << 10));
    float sf = 0.f, sa = 0.f;
    #pragma unroll
    for (int it = 0; it < 4; ++it) {
        float4 xv = xp[lane + (it << 6)];
        float4 cv = cp[lane + (it << 6)];
        sf += xv.x * cv.x + xv.y * cv.y + xv.z * cv.z + xv.w * cv.w;
        sa += xv.x + xv.y + xv.z + xv.w;
    }
    for (int off = 32; off > 0; off >>= 1) { sf += __shfl_xor(sf, off); sa += __shfl_xor(sa, off); }
    if (lane == 0) {
        float fgv = sf * (1.f / HW);
        out_fg[(n << 10) + c] = fgv;
        out_bg[(n << 10) + c] = sa * (1.f / HW) - fgv;
    }
}

__global__ void cvt_w(const float* __restrict__ qw, const float* __restrict__ kw,
                      const float* __restrict__ vw, ushort* __restrict__ wh) {
    size_t e = ((size_t)blockIdx.x * 256 + threadIdx.x) * 4;
    float4 v;
    if (e < 131072)       v = *(const float4*)(qw + e);
    else if (e < 262144)  v = *(const float4*)(kw + e - 131072);
    else                  v = *(const float4*)(vw + e - 262144);
    ushort4 h4;
    h4.x = f16b(v.x); h4.y = f16b(v.y); h4.z = f16b(v.z); h4.w = f16b(v.w);
    *(ushort4*)&wh[e] = h4;
}

// ============ fp16 MFMA GEMM core: 128x128 tile, BK=64, ZERO-LDS main loop.
// Both operands read directly from L1/L2 as 16B/lane fragments (lanes
// {l,l+16,l+32,l+48} = one 64B line) with ONE-TILE-AHEAD register prefetch:
// tile k+1's 16 fragment loads issue before tile k's MFMAs, so ~600 cyc of
// compute covers the ~200 cyc L2 latency (round-9 failed with 0-ahead).
// Fully unrolled (K constexpr) -> static reg indexing, no barriers, no LDS.
template<int K>
__device__ __forceinline__ void gemm_loop_reg(
        const ushort* __restrict__ Ag, int ap,
        const ushort* __restrict__ Bg, int bp,
        f32x4 acc[4][4]) {
    const int t = threadIdx.x;
    const int lane = t & 63, w = t >> 6;
    const int lr = lane & 15, kg = lane >> 4;
    const int wm = (w >> 1) << 6, wn = (w & 1) << 6;
    const ushort* pa[4];
    const ushort* pb[4];
    #pragma unroll
    for (int i = 0; i < 4; ++i) {
        pa[i] = Ag + (size_t)(wm + i * 16 + lr) * ap + kg * 8;
        pb[i] = Bg + (size_t)(wn + i * 16 + lr) * bp + kg * 8;
    }
    constexpr int NT = K >> 6;
    f16x8 ca[8], cb[8], na[8], nb[8];
    #pragma unroll
    for (int i = 0; i < 4; ++i)
        #pragma unroll
        for (int s = 0; s < 2; ++s) {
            ca[i * 2 + s] = *(const f16x8*)&pa[i][s << 5];
            cb[i * 2 + s] = *(const f16x8*)&pb[i][s << 5];
        }
    #pragma unroll
    for (int tile = 0; tile < NT; ++tile) {
        if (tile + 1 < NT) {
            int kb = (tile + 1) << 6;
            #pragma unroll
            for (int i = 0; i < 4; ++i)
                #pragma unroll
                for (int s = 0; s < 2; ++s) {
                    na[i * 2 + s] = *(const f16x8*)&pa[i][kb + (s << 5)];
                    nb[i * 2 + s] = *(const f16x8*)&pb[i][kb + (s << 5)];
                }
        }
        #pragma unroll
        for (int s = 0; s < 2; ++s)
            #pragma unroll
            for (int i = 0; i < 4; ++i)
                #pragma unroll
                for (int j = 0; j < 4; ++j)
                    acc[i][j] = __builtin_amdgcn_mfma_f32_16x16x32_f16(
                        ca[i * 2 + s], cb[j * 2 + s], acc[i][j], 0, 0, 0);
        if (tile + 1 < NT) {
            #pragma unroll
            for (int q = 0; q < 8; ++q) { ca[q] = na[q]; cb[q] = nb[q]; }
        }
    }
}

__global__ __launch_bounds__(256) void qkv_f16(
        const ushort* __restrict__ Wh, const ushort* __restrict__ xh,
        const float* __restrict__ qb, const float* __restrict__ kb,
        const float* __restrict__ vb,
        ushort* __restrict__ qt, ushort* __restrict__ kt, ushort* __restrict__ v) {
    __shared__ __align__(16) ushort lds[17408];   // epilogue v-transpose only (128x136)
    int n = blockIdx.z, m0 = blockIdx.y << 7, j0 = blockIdx.x << 7;
    f32x4 acc[4][4];
    #pragma unroll
    for (int i = 0; i < 4; ++i)
        #pragma unroll
        for (int j = 0; j < 4; ++j) acc[i][j] = (f32x4){0.f, 0.f, 0.f, 0.f};
    gemm_loop_reg<CC>(Wh + (size_t)m0 * CC, CC,
                      xh + ((size_t)(n * HW + j0)) * CC, CC, acc);
    const int t = threadIdx.x, lane = t & 63, wid = t >> 6;
    const int lr = lane & 15, kg = lane >> 4;
    const int wm = (wid >> 1) << 6, wn = (wid & 1) << 6;
    if (m0 < 256) {
        ushort* dst = (m0 == 0) ? qt : kt;
        const float* bp = (m0 == 0) ? qb : kb;
        #pragma unroll
        for (int mi = 0; mi < 4; ++mi)
            #pragma unroll
            for (int nj = 0; nj < 4; ++nj) {
                int m = wm + mi * 16 + kg * 4;
                int j = j0 + wn + nj * 16 + lr;
                ushort4 pk;
                pk.x = f16b(acc[mi][nj][0] + bp[m + 0]);
                pk.y = f16b(acc[mi][nj][1] + bp[m + 1]);
                pk.z = f16b(acc[mi][nj][2] + bp[m + 2]);
                pk.w = f16b(acc[mi][nj][3] + bp[m + 3]);
                *(ushort4*)&dst[((size_t)(n * HW + j) << 7) + m] = pk;
            }
    } else {
        int mo = m0 - 256;
        #pragma unroll
        for (int mi = 0; mi < 4; ++mi)
            #pragma unroll
            for (int nj = 0; nj < 4; ++nj) {
                int ml = wm + mi * 16 + kg * 4;
                int jl = wn + nj * 16 + lr;
                #pragma unroll
                for (int r = 0; r < 4; ++r)
                    lds[(ml + r) * 136 + jl] = f16b(acc[mi][nj][r] + vb[mo + ml + r]);
            }
        __syncthreads();
        #pragma unroll
        for (int p = 0; p < 8; ++p) {
            int row = (t >> 4) + p * 16;
            int ch = (t & 15) * 8;
            *(uint4*)&v[((size_t)(n * CC + mo + row) << 10) + j0 + ch] =
                *(const uint4*)&lds[row * 136 + ch];
        }
    }
}

__global__ __launch_bounds__(256) void score_f16(
        const ushort* __restrict__ qt, const ushort* __restrict__ kt,
        float* __restrict__ attn) {
    int n = blockIdx.z, i0 = blockIdx.y << 7, j0 = blockIdx.x << 7;
    f32x4 acc[4][4];
    #pragma unroll
    for (int i = 0; i < 4; ++i)
        #pragma unroll
        for (int j = 0; j < 4; ++j) acc[i][j] = (f32x4){0.f, 0.f, 0.f, 0.f};
    gemm_loop_reg<CQK>(qt + ((size_t)(n * HW + i0)) * CQK, CQK,
                       kt + ((size_t)(n * HW + j0)) * CQK, CQK, acc);
    const int t = threadIdx.x, lane = t & 63, wid = t >> 6;
    const int lr = lane & 15, kg = lane >> 4;
    const int wm = (wid >> 1) << 6, wn = (wid & 1) << 6;
    #pragma unroll
    for (int mi = 0; mi < 4; ++mi)
        #pragma unroll
        for (int r = 0; r < 4; ++r) {
            int irow = i0 + wm + mi * 16 + kg * 4 + r;
            #pragma unroll
            for (int nj = 0; nj < 4; ++nj) {
                int j = j0 + wn + nj * 16 + lr;
                attn[((size_t)(n * HW + irow) << 10) + j] = acc[mi][nj][r];
            }
        }
}

// row softmax; float4/ushort4 vectorized; P fp16 written in place
__global__ void softmax_f16(float* __restrict__ attn) {
    int row = blockIdx.x;
    float* p = attn + ((size_t)row << 10);
    int t = threadIdx.x;
    int wid = t >> 6, lane = t & 63;
    float4 v4 = *(const float4*)&p[t << 2];
    float m = fmaxf(fmaxf(v4.x, v4.y), fmaxf(v4.z, v4.w));
    for (int off = 32; off > 0; off >>= 1) m = fmaxf(m, __shfl_xor(m, off));
    __shared__ float redm[4], reds[4];
    if (lane == 0) redm[wid] = m;
    __syncthreads();
    if (t == 0) {
        float mm = fmaxf(fmaxf(redm[0], redm[1]), fmaxf(redm[2], redm[3]));
        redm[0] = mm;
    }
    __syncthreads();
    m = redm[0];
    v4.x = expf(v4.x - m); v4.y = expf(v4.y - m);
    v4.z = expf(v4.z - m); v4.w = expf(v4.w - m);
    float s = v4.x + v4.y + v4.z + v4.w;
    for (int off = 32; off > 0; off >>= 1) s += __shfl_xor(s, off);
    if (lane == 0) reds[wid] = s;
    __syncthreads();
    if (t == 0) reds[0] = reds[0] + reds[1] + reds[2] + reds[3];
    __syncthreads();
    float inv = 1.f / reds[0];
    ushort4 h4;
    h4.x = f16b(v4.x * inv); h4.y = f16b(v4.y * inv);
    h4.z = f16b(v4.z * inv); h4.w = f16b(v4.w * inv);
    *(ushort4*)&((ushort*)p)[t << 2] = h4;
}

__global__ __launch_bounds__(256) void out_f16(
        const ushort* __restrict__ v, const ushort* __restrict__ pus,
        const float* __restrict__ x, const float* __restrict__ gamma,
        float* __restrict__ pmax) {
    __shared__ float smax[4][64];
    int n = blockIdx.z, c0 = blockIdx.y << 7, i0 = blockIdx.x << 7;
    f32x4 acc[4][4];
    #pragma unroll
    for (int i = 0; i < 4; ++i)
        #pragma unroll
        for (int j = 0; j < 4; ++j) acc[i][j] = (f32x4){0.f, 0.f, 0.f, 0.f};
    gemm_loop_reg<HW>(v + ((size_t)(n * CC + c0) << 10), HW,
                      pus + ((size_t)(n * HW + i0)) * 2048, 2048, acc);
    const int t = threadIdx.x, lane = t & 63, wid = t >> 6;
    const int lr = lane & 15, kg = lane >> 4;
    const int wm = (wid >> 1) << 6, wn = (wid & 1) << 6;
    float g = gamma[0];
    #pragma unroll
    for (int mi = 0; mi < 4; ++mi)
        #pragma unroll
        for (int r = 0; r < 4; ++r) {
            int c = c0 + wm + mi * 16 + kg * 4 + r;
            const float* xp = x + ((size_t)(n * CC + c) << 10);
            float mx = -INFINITY;
            #pragma unroll
            for (int nj = 0; nj < 4; ++nj) {
                int i = i0 + wn + nj * 16 + lr;
                mx = fmaxf(mx, g * acc[mi][nj][r] + xp[i]);
            }
            #pragma unroll
            for (int off = 1; off < 16; off <<= 1) mx = fmaxf(mx, __shfl_xor(mx, off));
            if (lr == 0) smax[wid][mi * 16 + kg * 4 + r] = mx;
        }
    __syncthreads();
    if (t < 128) {
        int half = t >> 6, cl = t & 63;
        float m = fmaxf(smax[half * 2][cl], smax[half * 2 + 1][cl]);
        pmax[((size_t)(n * 8 + blockIdx.x) << 10) + c0 + half * 64 + cl] = m;
    }
}

__global__ void gf_reduce(const float* __restrict__ pmax, float* __restrict__ gf) {
    int idx = blockIdx.x * 256 + threadIdx.x;
    int n = idx >> 10, c = idx & 1023;
    float m = -INFINITY;
    #pragma unroll
    for (int ib = 0; ib < 8; ++ib)
        m = fmaxf(m, pmax[(((size_t)(n << 3) + ib) << 10) + c]);
    gf[idx] = m;
}

extern "C" void kernel_launch(void* const* d_in, const int* in_sizes, int n_in,
                              void* d_out, int out_size, void* d_ws, size_t ws_size,
                              hipStream_t stream) {
    const float* x      = (const float*)d_in[0];
    const float* head_w = (const float*)d_in[1];
    const float* bn_w   = (const float*)d_in[2];
    const float* bn_b   = (const float*)d_in[3];
    const float* q_w    = (const float*)d_in[4];
    const float* q_b    = (const float*)d_in[5];
    const float* k_w    = (const float*)d_in[6];
    const float* k_b    = (const float*)d_in[7];
    const float* v_w    = (const float*)d_in[8];
    const float* v_b    = (const float*)d_in[9];
    const float* gamma  = (const float*)d_in[10];

    float* out      = (float*)d_out;
    float* out_fg   = out;
    float* out_bg   = out + 16384;
    float* out_ccam = out + 32768;
    float* out_gf   = out + 49152;

    char* B = (char*)d_ws;
    float*  a     = (float*)(B + OFF_A);
    float*  stats = (float*)(B + OFF_STATS);
    float*  cm    = (float*)(B + OFF_CM);
    ushort* Wh    = (ushort*)(B + OFF_WH);
    ushort* qt    = (ushort*)(B + OFF_QT);
    ushort* kt    = (ushort*)(B + OFF_KT);
    ushort* v     = (ushort*)(B + OFF_V);
    ushort* xh    = (ushort*)(B + OFF_XH);
    float*  attn  = (float*)(B + OFF_ATTN);
    float*  pmax  = (float*)(B + OFF_PMAX);
    float*  ypart = (float*)(B + OFF_YP);

    hipLaunchKernelGGL(cvtT_x_conv, dim3(32, 32, 16), dim3(256), 0, stream, x, head_w, xh, ypart);
    hipLaunchKernelGGL(conv_combine, dim3(64), dim3(256), 0, stream, ypart, a);
    hipLaunchKernelGGL(bn_stats, dim3(1), dim3(256), 0, stream, a, stats);
    hipLaunchKernelGGL(ccam_kernel, dim3(64), dim3(256), 0, stream, a, stats, bn_w, bn_b, cm, out_ccam);
    hipLaunchKernelGGL(fgbg_kernel, dim3(4096), dim3(256), 0, stream, x, cm, out_fg, out_bg);

    hipLaunchKernelGGL(cvt_w, dim3(1280), dim3(256), 0, stream, q_w, k_w, v_w, Wh);
    hipLaunchKernelGGL(qkv_f16, dim3(8, 10, 16), dim3(256), 0, stream,
                       Wh, xh, q_b, k_b, v_b, qt, kt, v);
    hipLaunchKernelGGL(score_f16, dim3(8, 8, 16), dim3(256), 0, stream, qt, kt, attn);
    hipLaunchKernelGGL(softmax_f16, dim3(NB * HW), dim3(256), 0, stream, attn);
    hipLaunchKernelGGL(out_f16, dim3(8, 8, 16), dim3(256), 0, stream,
                       v, (const ushort*)attn, x, gamma, pmax);
    hipLaunchKernelGGL(gf_reduce, dim3(64), dim3(256), 0, stream, pmax, out_gf);
}

// Round 11
// 333.051 us; speedup vs baseline: 1.6401x; 1.6401x over previous
//
#include <hip/hip_runtime.h>
#include <math.h>

typedef _Float16 f16x8 __attribute__((ext_vector_type(8)));
typedef float f32x4 __attribute__((ext_vector_type(4)));

#define NB 16
#define CC 1024
#define HW 1024
#define CQK 128
#define EPS 1e-5f

// ---- ws byte offsets (~112 MiB) ----
#define OFF_A     0
#define OFF_STATS 65536
#define OFF_CM    66048
#define OFF_WH    131584                    /* W fp16 [1280][1024] = 2.5 MB */
#define OFF_QT    (OFF_WH + 2621440)        /* qT fp16 [16][1024][128] = 4 MB */
#define OFF_KT    (OFF_QT + 4194304)
#define OFF_V     (OFF_KT + 4194304)        /* v fp16 [16][1024][1024] = 32 MB */
#define OFF_XH    (OFF_V + 33554432)        /* xT fp16 [16][1024][1024] = 32 MB */
#define OFF_ATTN  OFF_XH                    /* attn fp32 64 MB overlays XH (dead after qkv) */
#define OFF_PMAX  (OFF_ATTN + 67108864)
#define OFF_YP    OFF_V                     /* conv partials, dead before qkv */

__device__ __forceinline__ ushort f16b(float f) {
    union { _Float16 h; ushort u; } v;
    v.h = (_Float16)f;
    return v.u;
}

// async global->LDS, 16B/lane; LDS dest = wave-uniform base + lane*16
__device__ __forceinline__ void gl_lds16(const void* g, void* s) {
    __builtin_amdgcn_global_load_lds(
        (const __attribute__((address_space(1))) void*)g,
        (__attribute__((address_space(3))) void*)s, 16, 0, 0);
}

// ============ cvtT_x + fused conv 9-tap partials ============
__global__ __launch_bounds__(256) void cvtT_x_conv(
        const float* __restrict__ x, const float* __restrict__ hwt,
        ushort* __restrict__ xh, float* __restrict__ yp) {
    int n = blockIdx.z, cb = blockIdx.y, hb = blockIdx.x;
    __shared__ float tile[32][33];
    int t = threadIdx.x;
    int r = t >> 3, c4 = (t & 7) << 2;
    const float* s = x + ((size_t)(n * CC + cb * 32 + r) << 10) + hb * 32 + c4;
    float4 v = *(const float4*)s;
    tile[r][c4] = v.x; tile[r][c4 + 1] = v.y; tile[r][c4 + 2] = v.z; tile[r][c4 + 3] = v.w;
    __syncthreads();
    int hw_l = t >> 3, cg = (t & 7) << 2;
    ushort4 h4;
    h4.x = f16b(tile[cg + 0][hw_l]); h4.y = f16b(tile[cg + 1][hw_l]);
    h4.z = f16b(tile[cg + 2][hw_l]); h4.w = f16b(tile[cg + 3][hw_l]);
    *(ushort4*)&xh[((size_t)(n * HW + hb * 32 + hw_l) << 10) + cb * 32 + cg] = h4;
    float pacc[9] = {};
    #pragma unroll
    for (int cc = 0; cc < 4; ++cc) {
        float xv = tile[cg + cc][hw_l];
        const float* w9 = hwt + (cb * 32 + cg + cc) * 9;
        #pragma unroll
        for (int tp = 0; tp < 9; ++tp) pacc[tp] += xv * w9[tp];
    }
    #pragma unroll
    for (int off = 1; off < 8; off <<= 1)
        #pragma unroll
        for (int tp = 0; tp < 9; ++tp) pacc[tp] += __shfl_xor(pacc[tp], off);
    if ((t & 7) == 0) {
        #pragma unroll
        for (int tp = 0; tp < 9; ++tp)
            yp[(((size_t)(n * 32 + cb) * 9 + tp) << 10) + hb * 32 + hw_l] = pacc[tp];
    }
}

__global__ __launch_bounds__(256) void conv_combine(
        const float* __restrict__ yp, float* __restrict__ a) {
    int idx = blockIdx.x * 256 + threadIdx.x;
    int n = idx >> 10, p = idx & 1023;
    int h = p >> 5, w = p & 31;
    float s = 0.f;
    #pragma unroll
    for (int tp = 0; tp < 9; ++tp) {
        int dy = tp / 3 - 1, dx = tp % 3 - 1;
        int hh = h + dy, ww = w + dx;
        if (hh < 0 || hh > 31 || ww < 0 || ww > 31) continue;
        int pp = (hh << 5) + ww;
        const float* b = yp + (((size_t)(n * 32) * 9) << 10) + ((size_t)tp << 10) + pp;
        #pragma unroll
        for (int cch = 0; cch < 32; ++cch) s += b[((size_t)cch * 9) << 10];
    }
    a[idx] = s;
}

// ============ small kernels ============
__global__ void bn_stats(const float* __restrict__ a, float* __restrict__ stats) {
    int t = threadIdx.x;
    float s = 0.f, ss = 0.f;
    for (int i = t; i < NB * HW; i += 256) { float v = a[i]; s += v; ss += v * v; }
    __shared__ float rs[256], rss[256];
    rs[t] = s; rss[t] = ss;
    __syncthreads();
    for (int off = 128; off > 0; off >>= 1) {
        if (t < off) { rs[t] += rs[t + off]; rss[t] += rss[t + off]; }
        __syncthreads();
    }
    if (t == 0) {
        float mu = rs[0] / (NB * HW);
        float var = rss[0] / (NB * HW) - mu * mu;
        stats[0] = mu;
        stats[1] = rsqrtf(var + EPS);
    }
}

__global__ void ccam_kernel(const float* __restrict__ a, const float* __restrict__ stats,
                            const float* __restrict__ bn_w, const float* __restrict__ bn_b,
                            float* __restrict__ cm, float* __restrict__ out_ccam) {
    int i = blockIdx.x * 256 + threadIdx.x;
    float z = (a[i] - stats[0]) * stats[1] * bn_w[0] + bn_b[0];
    float sg = 1.f / (1.f + expf(-z));
    cm[i] = sg;
    out_ccam[i] = sg;
}

__global__ void fgbg_kernel(const float* __restrict__ x, const float* __restrict__ cm,
                            float* __restrict__ out_fg, float* __restrict__ out_bg) {
    int gid = blockIdx.x * blockDim.x + threadIdx.x;
    int wid = gid >> 6;
    int lane = threadIdx.x & 63;
    int n = wid >> 10, c = wid & 1023;
    const float4* xp = (const float4*)(x + ((size_t)(n * CC + c) << 10));
    const float4* cp = (const float4*)(cm + (n << 10));
    float sf = 0.f, sa = 0.f;
    #pragma unroll
    for (int it = 0; it < 4; ++it) {
        float4 xv = xp[lane + (it << 6)];
        float4 cv = cp[lane + (it << 6)];
        sf += xv.x * cv.x + xv.y * cv.y + xv.z * cv.z + xv.w * cv.w;
        sa += xv.x + xv.y + xv.z + xv.w;
    }
    for (int off = 32; off > 0; off >>= 1) { sf += __shfl_xor(sf, off); sa += __shfl_xor(sa, off); }
    if (lane == 0) {
        float fgv = sf * (1.f / HW);
        out_fg[(n << 10) + c] = fgv;
        out_bg[(n << 10) + c] = sa * (1.f / HW) - fgv;
    }
}

__global__ void cvt_w(const float* __restrict__ qw, const float* __restrict__ kw,
                      const float* __restrict__ vw, ushort* __restrict__ wh) {
    size_t e = ((size_t)blockIdx.x * 256 + threadIdx.x) * 4;
    float4 v;
    if (e < 131072)       v = *(const float4*)(qw + e);
    else if (e < 262144)  v = *(const float4*)(kw + e - 131072);
    else                  v = *(const float4*)(vw + e - 262144);
    ushort4 h4;
    h4.x = f16b(v.x); h4.y = f16b(v.y); h4.z = f16b(v.z); h4.w = f16b(v.w);
    *(ushort4*)&wh[e] = h4;
}

// ============ fp16 MFMA GEMM core: 128x128 tile, BK=64, XOR-swizzled gl_lds,
// 2-phase double-buffer with COUNTED vmcnt (T4): per tile, issue next tile's
// 8 gl_lds, then s_waitcnt vmcnt(8) (waits ONLY the current tile's loads,
// keeps 8 in flight across the barrier), raw s_barrier, compute, raw
// s_barrier. No vmcnt(0) drain except the final tile. LDS = 2 x 32 KB.
__device__ __forceinline__ void gemm_loop_f16(
        const ushort* __restrict__ Ag, int ap,
        const ushort* __restrict__ Bg, int bp,
        int K, ushort* lds, f32x4 acc[4][4]) {
    const int t = threadIdx.x;
    const int lane = t & 63, w = t >> 6;
    const int lr = lane & 15, kg = lane >> 4;
    const int wm = (w >> 1) << 6, wn = (w & 1) << 6;
    const int rowl = lane >> 3;
    const int cs = (lane & 7) ^ rowl;    // swizzled source chunk (both-sides rule)
    const int ldsb = w << 9;
    const int cA0 = kg ^ (lr & 7);
    const int cA1 = (kg | 4) ^ (lr & 7);
    // loop-invariant per-lane global row pointers
    const ushort* gA[4];
    const ushort* gB[4];
    #pragma unroll
    for (int q = 0; q < 4; ++q) {
        int r = (w << 3) + rowl + (q << 5);
        gA[q] = Ag + cs * 8 + (size_t)r * ap;
        gB[q] = Bg + cs * 8 + (size_t)r * bp;
    }
    const int nt = K >> 6;
    // prologue: stage tile 0 into buf 0
    #pragma unroll
    for (int q = 0; q < 4; ++q) {
        gl_lds16(gA[q], lds + ldsb + (q << 11));
        gl_lds16(gB[q], lds + 8192 + ldsb + (q << 11));
    }
    int buf = 0;
    for (int tile = 0; tile < nt; ++tile) {
        if (tile + 1 < nt) {
            int nb = (buf ^ 1) << 14;
            int k0 = (tile + 1) << 6;
            #pragma unroll
            for (int q = 0; q < 4; ++q) {
                gl_lds16(gA[q] + k0, lds + nb + ldsb + (q << 11));
                gl_lds16(gB[q] + k0, lds + nb + 8192 + ldsb + (q << 11));
            }
            asm volatile("s_waitcnt vmcnt(8)" ::: "memory");
        } else {
            asm volatile("s_waitcnt vmcnt(0)" ::: "memory");
        }
        __builtin_amdgcn_s_barrier();           // all waves: current buffer resident
        asm volatile("" ::: "memory");
        const ushort* Ab = lds + (buf << 14);
        const ushort* Bb = Ab + 8192;
        #pragma unroll
        for (int s = 0; s < 2; ++s) {
            int ch = s ? cA1 : cA0;
            f16x8 a[4], b[4];
            #pragma unroll
            for (int i = 0; i < 4; ++i) {
                a[i] = *(const f16x8*)&Ab[((wm + i * 16 + lr) << 6) + ch * 8];
                b[i] = *(const f16x8*)&Bb[((wn + i * 16 + lr) << 6) + ch * 8];
            }
            #pragma unroll
            for (int i = 0; i < 4; ++i)
                #pragma unroll
                for (int j = 0; j < 4; ++j)
                    acc[i][j] = __builtin_amdgcn_mfma_f32_16x16x32_f16(a[i], b[j], acc[i][j], 0, 0, 0);
        }
        asm volatile("" ::: "memory");
        __builtin_amdgcn_s_barrier();           // all waves done reading buf before restage
        buf ^= 1;
    }
}

__global__ __launch_bounds__(256) void qkv_f16(
        const ushort* __restrict__ Wh, const ushort* __restrict__ xh,
        const float* __restrict__ qb, const float* __restrict__ kb,
        const float* __restrict__ vb,
        ushort* __restrict__ qt, ushort* __restrict__ kt, ushort* __restrict__ v) {
    __shared__ __align__(16) ushort lds[32768];   // 64 KB dbuf; epilogue reuse
    int n = blockIdx.z, m0 = blockIdx.y << 7, j0 = blockIdx.x << 7;
    f32x4 acc[4][4];
    #pragma unroll
    for (int i = 0; i < 4; ++i)
        #pragma unroll
        for (int j = 0; j < 4; ++j) acc[i][j] = (f32x4){0.f, 0.f, 0.f, 0.f};
    gemm_loop_f16(Wh + (size_t)m0 * CC, CC,
                  xh + ((size_t)(n * HW + j0)) * CC, CC, CC, lds, acc);
    const int t = threadIdx.x, lane = t & 63, wid = t >> 6;
    const int lr = lane & 15, kg = lane >> 4;
    const int wm = (wid >> 1) << 6, wn = (wid & 1) << 6;
    if (m0 < 256) {
        ushort* dst = (m0 == 0) ? qt : kt;
        const float* bp = (m0 == 0) ? qb : kb;
        #pragma unroll
        for (int mi = 0; mi < 4; ++mi)
            #pragma unroll
            for (int nj = 0; nj < 4; ++nj) {
                int m = wm + mi * 16 + kg * 4;
                int j = j0 + wn + nj * 16 + lr;
                ushort4 pk;
                pk.x = f16b(acc[mi][nj][0] + bp[m + 0]);
                pk.y = f16b(acc[mi][nj][1] + bp[m + 1]);
                pk.z = f16b(acc[mi][nj][2] + bp[m + 2]);
                pk.w = f16b(acc[mi][nj][3] + bp[m + 3]);
                *(ushort4*)&dst[((size_t)(n * HW + j) << 7) + m] = pk;
            }
    } else {
        int mo = m0 - 256;
        __syncthreads();   // staging dead; reuse as transpose buffer (128x136)
        #pragma unroll
        for (int mi = 0; mi < 4; ++mi)
            #pragma unroll
            for (int nj = 0; nj < 4; ++nj) {
                int ml = wm + mi * 16 + kg * 4;
                int jl = wn + nj * 16 + lr;
                #pragma unroll
                for (int r = 0; r < 4; ++r)
                    lds[(ml + r) * 136 + jl] = f16b(acc[mi][nj][r] + vb[mo + ml + r]);
            }
        __syncthreads();
        #pragma unroll
        for (int p = 0; p < 8; ++p) {
            int row = (t >> 4) + p * 16;
            int ch = (t & 15) * 8;
            *(uint4*)&v[((size_t)(n * CC + mo + row) << 10) + j0 + ch] =
                *(const uint4*)&lds[row * 136 + ch];
        }
    }
}

__global__ __launch_bounds__(256) void score_f16(
        const ushort* __restrict__ qt, const ushort* __restrict__ kt,
        float* __restrict__ attn) {
    __shared__ __align__(16) ushort lds[32768];
    int n = blockIdx.z, i0 = blockIdx.y << 7, j0 = blockIdx.x << 7;
    f32x4 acc[4][4];
    #pragma unroll
    for (int i = 0; i < 4; ++i)
        #pragma unroll
        for (int j = 0; j < 4; ++j) acc[i][j] = (f32x4){0.f, 0.f, 0.f, 0.f};
    gemm_loop_f16(qt + ((size_t)(n * HW + i0)) * CQK, CQK,
                  kt + ((size_t)(n * HW + j0)) * CQK, CQK, CQK, lds, acc);
    const int t = threadIdx.x, lane = t & 63, wid = t >> 6;
    const int lr = lane & 15, kg = lane >> 4;
    const int wm = (wid >> 1) << 6, wn = (wid & 1) << 6;
    #pragma unroll
    for (int mi = 0; mi < 4; ++mi)
        #pragma unroll
        for (int r = 0; r < 4; ++r) {
            int irow = i0 + wm + mi * 16 + kg * 4 + r;
            #pragma unroll
            for (int nj = 0; nj < 4; ++nj) {
                int j = j0 + wn + nj * 16 + lr;
                attn[((size_t)(n * HW + irow) << 10) + j] = acc[mi][nj][r];
            }
        }
}

// row softmax; float4/ushort4 vectorized; P fp16 written in place
__global__ void softmax_f16(float* __restrict__ attn) {
    int row = blockIdx.x;
    float* p = attn + ((size_t)row << 10);
    int t = threadIdx.x;
    int wid = t >> 6, lane = t & 63;
    float4 v4 = *(const float4*)&p[t << 2];
    float m = fmaxf(fmaxf(v4.x, v4.y), fmaxf(v4.z, v4.w));
    for (int off = 32; off > 0; off >>= 1) m = fmaxf(m, __shfl_xor(m, off));
    __shared__ float redm[4], reds[4];
    if (lane == 0) redm[wid] = m;
    __syncthreads();
    if (t == 0) {
        float mm = fmaxf(fmaxf(redm[0], redm[1]), fmaxf(redm[2], redm[3]));
        redm[0] = mm;
    }
    __syncthreads();
    m = redm[0];
    v4.x = expf(v4.x - m); v4.y = expf(v4.y - m);
    v4.z = expf(v4.z - m); v4.w = expf(v4.w - m);
    float s = v4.x + v4.y + v4.z + v4.w;
    for (int off = 32; off > 0; off >>= 1) s += __shfl_xor(s, off);
    if (lane == 0) reds[wid] = s;
    __syncthreads();
    if (t == 0) reds[0] = reds[0] + reds[1] + reds[2] + reds[3];
    __syncthreads();
    float inv = 1.f / reds[0];
    ushort4 h4;
    h4.x = f16b(v4.x * inv); h4.y = f16b(v4.y * inv);
    h4.z = f16b(v4.z * inv); h4.w = f16b(v4.w * inv);
    *(ushort4*)&((ushort*)p)[t << 2] = h4;
}

__global__ __launch_bounds__(256) void out_f16(
        const ushort* __restrict__ v, const ushort* __restrict__ pus,
        const float* __restrict__ x, const float* __restrict__ gamma,
        float* __restrict__ pmax) {
    __shared__ __align__(16) ushort lds[32768];
    int n = blockIdx.z, c0 = blockIdx.y << 7, i0 = blockIdx.x << 7;
    f32x4 acc[4][4];
    #pragma unroll
    for (int i = 0; i < 4; ++i)
        #pragma unroll
        for (int j = 0; j < 4; ++j) acc[i][j] = (f32x4){0.f, 0.f, 0.f, 0.f};
    gemm_loop_f16(v + ((size_t)(n * CC + c0) << 10), HW,
                  pus + ((size_t)(n * HW + i0)) * 2048, 2048, HW, lds, acc);
    const int t = threadIdx.x, lane = t & 63, wid = t >> 6;
    const int lr = lane & 15, kg = lane >> 4;
    const int wm = (wid >> 1) << 6, wn = (wid & 1) << 6;
    float g = gamma[0];
    __syncthreads();
    float (*smax)[64] = (float(*)[64])lds;
    #pragma unroll
    for (int mi = 0; mi < 4; ++mi)
        #pragma unroll
        for (int r = 0; r < 4; ++r) {
            int c = c0 + wm + mi * 16 + kg * 4 + r;
            const float* xp = x + ((size_t)(n * CC + c) << 10);
            float mx = -INFINITY;
            #pragma unroll
            for (int nj = 0; nj < 4; ++nj) {
                int i = i0 + wn + nj * 16 + lr;
                mx = fmaxf(mx, g * acc[mi][nj][r] + xp[i]);
            }
            #pragma unroll
            for (int off = 1; off < 16; off <<= 1) mx = fmaxf(mx, __shfl_xor(mx, off));
            if (lr == 0) smax[wid][mi * 16 + kg * 4 + r] = mx;
        }
    __syncthreads();
    if (t < 128) {
        int half = t >> 6, cl = t & 63;
        float m = fmaxf(smax[half * 2][cl], smax[half * 2 + 1][cl]);
        pmax[((size_t)(n * 8 + blockIdx.x) << 10) + c0 + half * 64 + cl] = m;
    }
}

__global__ void gf_reduce(const float* __restrict__ pmax, float* __restrict__ gf) {
    int idx = blockIdx.x * 256 + threadIdx.x;
    int n = idx >> 10, c = idx & 1023;
    float m = -INFINITY;
    #pragma unroll
    for (int ib = 0; ib < 8; ++ib)
        m = fmaxf(m, pmax[(((size_t)(n << 3) + ib) << 10) + c]);
    gf[idx] = m;
}

extern "C" void kernel_launch(void* const* d_in, const int* in_sizes, int n_in,
                              void* d_out, int out_size, void* d_ws, size_t ws_size,
                              hipStream_t stream) {
    const float* x      = (const float*)d_in[0];
    const float* head_w = (const float*)d_in[1];
    const float* bn_w   = (const float*)d_in[2];
    const float* bn_b   = (const float*)d_in[3];
    const float* q_w    = (const float*)d_in[4];
    const float* q_b    = (const float*)d_in[5];
    const float* k_w    = (const float*)d_in[6];
    const float* k_b    = (const float*)d_in[7];
    const float* v_w    = (const float*)d_in[8];
    const float* v_b    = (const float*)d_in[9];
    const float* gamma  = (const float*)d_in[10];

    float* out      = (float*)d_out;
    float* out_fg   = out;
    float* out_bg   = out + 16384;
    float* out_ccam = out + 32768;
    float* out_gf   = out + 49152;

    char* B = (char*)d_ws;
    float*  a     = (float*)(B + OFF_A);
    float*  stats = (float*)(B + OFF_STATS);
    float*  cm    = (float*)(B + OFF_CM);
    ushort* Wh    = (ushort*)(B + OFF_WH);
    ushort* qt    = (ushort*)(B + OFF_QT);
    ushort* kt    = (ushort*)(B + OFF_KT);
    ushort* v     = (ushort*)(B + OFF_V);
    ushort* xh    = (ushort*)(B + OFF_XH);
    float*  attn  = (float*)(B + OFF_ATTN);
    float*  pmax  = (float*)(B + OFF_PMAX);
    float*  ypart = (float*)(B + OFF_YP);

    hipLaunchKernelGGL(cvtT_x_conv, dim3(32, 32, 16), dim3(256), 0, stream, x, head_w, xh, ypart);
    hipLaunchKernelGGL(conv_combine, dim3(64), dim3(256), 0, stream, ypart, a);
    hipLaunchKernelGGL(bn_stats, dim3(1), dim3(256), 0, stream, a, stats);
    hipLaunchKernelGGL(ccam_kernel, dim3(64), dim3(256), 0, stream, a, stats, bn_w, bn_b, cm, out_ccam);
    hipLaunchKernelGGL(fgbg_kernel, dim3(4096), dim3(256), 0, stream, x, cm, out_fg, out_bg);

    hipLaunchKernelGGL(cvt_w, dim3(1280), dim3(256), 0, stream, q_w, k_w, v_w, Wh);
    hipLaunchKernelGGL(qkv_f16, dim3(8, 10, 16), dim3(256), 0, stream,
                       Wh, xh, q_b, k_b, v_b, qt, kt, v);
    hipLaunchKernelGGL(score_f16, dim3(8, 8, 16), dim3(256), 0, stream, qt, kt, attn);
    hipLaunchKernelGGL(softmax_f16, dim3(NB * HW), dim3(256), 0, stream, attn);
    hipLaunchKernelGGL(out_f16, dim3(8, 8, 16), dim3(256), 0, stream,
                       v, (const ushort*)attn, x, gamma, pmax);
    hipLaunchKernelGGL(gf_reduce, dim3(64), dim3(256), 0, stream, pmax, out_gf);
}